// Round 9
// baseline (8816.024 us; speedup 1.0000x reference)
//
#include <hip/hip_runtime.h>
#include <hip/hip_bf16.h>

#if __has_builtin(__builtin_amdgcn_exp2f)
#define EXP2F(x) __builtin_amdgcn_exp2f(x)
#else
#define EXP2F(x) exp2f(x)
#endif
#if __has_builtin(__builtin_amdgcn_rcpf)
#define RCPF(x) __builtin_amdgcn_rcpf(x)
#else
#define RCPF(x) (1.0f/(x))
#endif

typedef _Float16 h2f16 __attribute__((ext_vector_type(2)));

namespace {
constexpr int   kT   = 127;
constexpr int   kE   = 128;
constexpr int   kB   = 4096;
constexpr int   kNWG = 256;
constexpr int   kGRP = 4;                  // batches processed simultaneously
constexpr int   kBPW = 16;                 // batches per workgroup (4 groups)
constexpr float kLog2e = 1.4426950408889634f;
constexpr float kK2    = 2.8853900817779268f;   // 2*log2(e)
constexpr int   kSmemBytes = (32768 + 256 + 640 + 6 * 512 + 128 + 256 + 132) * 4;

__device__ __forceinline__ unsigned int packf16(float a, float b) {
  h2f16 h = { (_Float16)a, (_Float16)b };
  return __builtin_bit_cast(unsigned int, h);
}

#if __has_builtin(__builtin_amdgcn_fdot2)
__device__ __forceinline__ float fdot2f(unsigned int a, unsigned int b, float c) {
  return __builtin_amdgcn_fdot2(__builtin_bit_cast(h2f16, a),
                                __builtin_bit_cast(h2f16, b), c, false);
}
#else
__device__ __forceinline__ float fdot2f(unsigned int a, unsigned int b, float c) {
  h2f16 ha = __builtin_bit_cast(h2f16, a), hb = __builtin_bit_cast(h2f16, b);
  return c + (float)ha.x * (float)hb.x + (float)ha.y * (float)hb.y;
}
#endif

// ---- DPP cross-lane (VALU-pipe, replaces ds_swizzle shuffles) ----
// ctrl: 0xB1 quad_perm[1,0,3,2] (xor1), 0x4E quad_perm[2,3,0,1] (xor2),
//       0x141 row_half_mirror (butterfly stage-3), 0x128 row_ror:8 (xor8 in 16).
template <int CTRL>
__device__ __forceinline__ float dppadd(float x) {
  return x + __int_as_float(__builtin_amdgcn_update_dpp(
      0, __float_as_int(x), CTRL, 0xF, 0xF, true));
}
template <int CTRL>
__device__ __forceinline__ float dppmov(float x) {
  return __int_as_float(__builtin_amdgcn_update_dpp(
      0, __float_as_int(x), CTRL, 0xF, 0xF, true));
}
__device__ __forceinline__ float redsum8dpp(float x) {   // sum over lane bits 0..2
  x = dppadd<0xB1>(x); x = dppadd<0x4E>(x); x = dppadd<0x141>(x);
  return x;
}
__device__ __forceinline__ float redsum16dpp(float x) {  // sum over lane bits 0..3
  x = dppadd<0xB1>(x); x = dppadd<0x4E>(x); x = dppadd<0x141>(x); x = dppadd<0x128>(x);
  return x;
}
__device__ __forceinline__ float redsum64dpp(float x) {  // full-wave sum
  x = redsum16dpp(x);
  x += __shfl_xor(x, 16, 64);
  x += __shfl_xor(x, 32, 64);
  return x;
}
__device__ __forceinline__ float redsum64(float a) {
#pragma unroll
  for (int m = 1; m < 64; m <<= 1) a += __shfl_xor(a, m, 64);
  return a;
}

// 1024 threads, 16 waves, 4 batches per step-group, 3 barriers/step.
// d8 = tid>>3 owns gate rows {i,f,g,o}[d8] (K-chunk sub*16) and score row d8.
// pg = tid>>4 owns proj rows {2pg, 2pg+1} (K-chunk (tid&15)*16).
__global__ __launch_bounds__(1024, 4) void decoder_kernel(
    const float* __restrict__ Xg,    // [B,127,128]
    const float* __restrict__ yh,    // [B,127]
    const float* __restrict__ vdw,   // [128]
    const float* __restrict__ vdb,   // [1]
    const float* __restrict__ Wdhs,  // [128,256]
    const float* __restrict__ Wdhsb, // [128]
    const float* __restrict__ Udw,   // [128,128]
    const float* __restrict__ Udb,   // [128]
    const float* __restrict__ ww,    // [129]
    const float* __restrict__ wb,    // [1]
    const float* __restrict__ Wih,   // [512]
    const float* __restrict__ Whh,   // [512,128]
    const float* __restrict__ bih,   // [512]
    const float* __restrict__ bhh,   // [512]
    const float* __restrict__ fcww,  // [256]
    const float* __restrict__ fcb,   // [1]
    float* __restrict__ out)         // [B]
{
  extern __shared__ char smem[];
  unsigned int* u2u  = (unsigned int*)smem;   // [4][128][64] f16 pairs, chunk c at c^(row&15)
  unsigned int* udw2 = u2u + 3 * 8192;        // staging scratch overlay on slot j=3
  unsigned int* p2h  = u2u + 4 * 8192;        // [4][64] f16 pairs of K2*(proj+b)
  unsigned int* hc2  = p2h + 256;             // [4][160]: pairs, 8 chunks of 16 + 4 pad (stride 20)
  float* sc   = (float*)(hc2 + 640);  // [4][128] raw scores
  float* XW   = sc   + 512;           // [4][128] ww . X[t,:]
  float* yc   = XW   + 512;           // [4][128] ww[128]*y + wb
  float* beta = yc   + 512;           // [4][128] softmax (last step only)
  float* hl   = beta + 512;           // [4][128] final h
  float* ctxl = hl   + 512;           // [4][128] final ctx
  float* udbl = ctxl + 512;           // [128]
  float* fcw  = udbl + 128;           // [256]
  float* wwl  = fcw  + 256;           // [132]

  const int tid  = threadIdx.x;
  const int d8   = tid >> 3;          // 0..127
  const int sub  = tid & 7;
  const int pg   = tid >> 4;          // 0..63
  const int k16  = tid & 15;
  const int lane = tid & 63;

  // ---- pinned per-thread weights: 66 persistent regs ----
  unsigned int whh[32];               // 4 gates x 8 pairs, rows g*128+d8, K in [sub*16,+16)
#pragma unroll
  for (int g = 0; g < 4; ++g)
#pragma unroll
    for (int p = 0; p < 8; ++p)
      whh[g * 8 + p] = packf16(Whh[(g * 128 + d8) * 128 + sub * 16 + 2 * p],
                               Whh[(g * 128 + d8) * 128 + sub * 16 + 2 * p + 1]);
  unsigned int wdq[16];               // proj rows 2pg,2pg+1; K-chunk k16*16..+16 (8 pairs each)
#pragma unroll
  for (int r = 0; r < 2; ++r)
#pragma unroll
    for (int q = 0; q < 8; ++q)
      wdq[r * 8 + q] = packf16(Wdhs[(2 * pg + r) * 256 + k16 * 16 + 2 * q],
                               Wdhs[(2 * pg + r) * 256 + k16 * 16 + 2 * q + 1]);
  unsigned int v2p[8];                // -2*v_d, e in [sub*16,+16), f16 pairs
#pragma unroll
  for (int i = 0; i < 8; ++i)
    v2p[i] = packf16(-2.0f * vdw[sub * 16 + 2 * i], -2.0f * vdw[sub * 16 + 2 * i + 1]);
  float bi4[4], wi4[4];
#pragma unroll
  for (int g = 0; g < 4; ++g) {
    bi4[g] = bih[g * 128 + d8] + bhh[g * 128 + d8];
    wi4[g] = Wih[g * 128 + d8];
  }
  float wdb0 = Wdhsb[2 * pg], wdb1 = Wdhsb[2 * pg + 1];
#pragma unroll
  for (int p = 0; p < 32; ++p) asm volatile("" : "+v"(whh[p]));
#pragma unroll
  for (int q = 0; q < 16; ++q) asm volatile("" : "+v"(wdq[q]));
#pragma unroll
  for (int i = 0; i < 8; ++i) asm volatile("" : "+v"(v2p[i]));
#pragma unroll
  for (int g = 0; g < 4; ++g) { asm volatile("" : "+v"(bi4[g])); asm volatile("" : "+v"(wi4[g])); }
  asm volatile("" : "+v"(wdb0));
  asm volatile("" : "+v"(wdb1));

  // ---- one-time constants ----
  if (tid < 132) wwl[tid] = (tid < 129) ? ww[tid] : ((tid == 129) ? wb[0] : 0.f);
  if (tid < 256) fcw[tid] = fcww[tid];
  if (tid < 128) udbl[tid] = Udb[tid];
  (void)vdb;   // constant shift, cancels in softmax

  for (int grp = 0; grp < kBPW / kGRP; ++grp) {
    const int b0 = blockIdx.x * kBPW + grp * kGRP;
    float creg[kGRP] = {0.f, 0.f, 0.f, 0.f};
    __syncthreads();   // previous group done with LDS

    // ---- S1: stage Udw f16 (swizzled) into slot3 scratch + init state/yc/XW pad ----
    {
      const int r = tid >> 3, mb = (tid & 7) * 2;
#pragma unroll
      for (int ch = 0; ch < 2; ++ch) {
        const int m = mb + ch;
        const float4 wa = *(const float4*)&Udw[r * kE + m * 8];
        const float4 wb4 = *(const float4*)&Udw[r * kE + m * 8 + 4];
        uint4 st;
        st.x = packf16(wa.x, wa.y);  st.y = packf16(wa.z, wa.w);
        st.z = packf16(wb4.x, wb4.y); st.w = packf16(wb4.z, wb4.w);
        *(uint4*)&udw2[r * 64 + ((m ^ (r >> 4)) << 2)] = st;
      }
    }
    if (tid < 640) hc2[tid] = 0u;
    if (tid < 512) {
      const int j = tid >> 7, s2 = tid & 127;
      yc[tid] = (s2 < kT) ? wwl[128] * yh[(size_t)(b0 + j) * kT + s2] + wwl[129] : 0.f;
      if (s2 == 127) XW[tid] = 0.f;
    }
    __syncthreads();

    // ---- S2: U2 = K2*(X @ Udw^T + Udb) (f16, swizzled) + XW, 4 batches ----
    uint4 st3a, st3b;
    if (d8 < kT) {
#pragma unroll
      for (int j = 0; j < kGRP; ++j) {
        const float* Xrow = Xg + (size_t)(b0 + j) * (kT * kE) + d8 * kE;
        float a = 0.f;
#pragma unroll
        for (int q = 0; q < 4; ++q) {
          const float4 xv = *(const float4*)&Xrow[sub * 16 + q * 4];
          const float4 wv = *(const float4*)&wwl[sub * 16 + q * 4];
          a += xv.x * wv.x + xv.y * wv.y + xv.z * wv.z + xv.w * wv.w;
        }
        a = redsum8dpp(a);
        if (sub == 0) XW[j * 128 + d8] = a;
        float acc[16];
#pragma unroll
        for (int jj = 0; jj < 16; ++jj) acc[jj] = 0.f;
        for (int m = 0; m < 16; ++m) {
          const float4 xa = *(const float4*)&Xrow[m * 8];
          const float4 xb4 = *(const float4*)&Xrow[m * 8 + 4];
          const unsigned int xp0 = packf16(xa.x, xa.y), xp1 = packf16(xa.z, xa.w);
          const unsigned int xp2 = packf16(xb4.x, xb4.y), xp3 = packf16(xb4.z, xb4.w);
#pragma unroll
          for (int jj = 0; jj < 16; ++jj) {
            const uint4 wq = *(const uint4*)&udw2[(sub * 16 + jj) * 64 + ((m ^ sub) << 2)];
            acc[jj] = fdot2f(xp3, wq.w, fdot2f(xp2, wq.z,
                      fdot2f(xp1, wq.y, fdot2f(xp0, wq.x, acc[jj]))));
          }
        }
        uint4 s0, s1;
        const int eb = sub * 16;
        s0.x = packf16(kK2 * (acc[0] + udbl[eb + 0]), kK2 * (acc[1] + udbl[eb + 1]));
        s0.y = packf16(kK2 * (acc[2] + udbl[eb + 2]), kK2 * (acc[3] + udbl[eb + 3]));
        s0.z = packf16(kK2 * (acc[4] + udbl[eb + 4]), kK2 * (acc[5] + udbl[eb + 5]));
        s0.w = packf16(kK2 * (acc[6] + udbl[eb + 6]), kK2 * (acc[7] + udbl[eb + 7]));
        s1.x = packf16(kK2 * (acc[8] + udbl[eb + 8]), kK2 * (acc[9] + udbl[eb + 9]));
        s1.y = packf16(kK2 * (acc[10] + udbl[eb + 10]), kK2 * (acc[11] + udbl[eb + 11]));
        s1.z = packf16(kK2 * (acc[12] + udbl[eb + 12]), kK2 * (acc[13] + udbl[eb + 13]));
        s1.w = packf16(kK2 * (acc[14] + udbl[eb + 14]), kK2 * (acc[15] + udbl[eb + 15]));
        if (j < 3) {
          *(uint4*)&u2u[j * 8192 + d8 * 64 + (((sub * 2 + 0) ^ (d8 & 15)) << 2)] = s0;
          *(uint4*)&u2u[j * 8192 + d8 * 64 + (((sub * 2 + 1) ^ (d8 & 15)) << 2)] = s1;
        } else { st3a = s0; st3b = s1; }
      }
    }
    __syncthreads();   // udw2 fully consumed
    if (d8 < kT) {
      *(uint4*)&u2u[3 * 8192 + d8 * 64 + (((sub * 2 + 0) ^ (d8 & 15)) << 2)] = st3a;
      *(uint4*)&u2u[3 * 8192 + d8 * 64 + (((sub * 2 + 1) ^ (d8 & 15)) << 2)] = st3b;
    }
    // (slot-3 stores separated from first read by B1 in the step loop)

    // ================= 127 steps x 4 batches, 3 barriers each =================
    for (int s = 0; s < kT; ++s) {
      // P1: gates (DPP 8-lane reduce; sums stay in registers in ALL lanes)
      //     + proj rows 2pg,2pg+1 (DPP 16-lane reduce; packed b32 store).
      float ga[16];
#pragma unroll
      for (int j = 0; j < kGRP; ++j) {
        const unsigned int* hj = hc2 + j * 160;
        const int gb = (sub >> 1) * 20 + (sub & 1) * 8;
        const uint4 h0 = *(const uint4*)&hj[gb];
        const uint4 h1 = *(const uint4*)&hj[gb + 4];
        const unsigned int hp[8] = {h0.x, h0.y, h0.z, h0.w, h1.x, h1.y, h1.z, h1.w};
        float a0 = 0.f, a1 = 0.f, a2 = 0.f, a3 = 0.f;
#pragma unroll
        for (int p = 0; p < 8; ++p) {
          a0 = fdot2f(whh[p], hp[p], a0);
          a1 = fdot2f(whh[8 + p], hp[p], a1);
          a2 = fdot2f(whh[16 + p], hp[p], a2);
          a3 = fdot2f(whh[24 + p], hp[p], a3);
        }
        ga[j * 4 + 0] = redsum8dpp(a0);
        ga[j * 4 + 1] = redsum8dpp(a1);
        ga[j * 4 + 2] = redsum8dpp(a2);
        ga[j * 4 + 3] = redsum8dpp(a3);
        const int pb = (k16 >> 1) * 20 + (k16 & 1) * 8;
        const uint4 q0 = *(const uint4*)&hj[pb];
        const uint4 q1 = *(const uint4*)&hj[pb + 4];
        const unsigned int pq[8] = {q0.x, q0.y, q0.z, q0.w, q1.x, q1.y, q1.z, q1.w};
        float p0 = 0.f, p1 = 0.f;
#pragma unroll
        for (int q = 0; q < 8; ++q) {
          p0 = fdot2f(wdq[q], pq[q], p0);
          p1 = fdot2f(wdq[8 + q], pq[q], p1);
        }
        p0 = redsum16dpp(p0);
        p1 = redsum16dpp(p1);
        if (k16 == 0)
          p2h[j * 64 + pg] = packf16(kK2 * (p0 + wdb0), kK2 * (p1 + wdb1));
      }
      __syncthreads();  // B1

      // P3: score row d8, e-chunk [sub*16,+16); DPP 8-lane reduce
      if (d8 < kT) {
        const int sw = d8 & 15;
#pragma unroll
        for (int j = 0; j < kGRP; ++j) {
          const unsigned int* ur = u2u + j * 8192 + d8 * 64;
          const uint4 ua = *(const uint4*)&ur[(((sub * 2 + 0) ^ sw) << 2)];
          const uint4 ub = *(const uint4*)&ur[(((sub * 2 + 1) ^ sw) << 2)];
          const uint4 pa = *(const uint4*)&p2h[j * 64 + sub * 8];
          const uint4 pb = *(const uint4*)&p2h[j * 64 + sub * 8 + 4];
          const unsigned int uu[8] = {ua.x, ua.y, ua.z, ua.w, ub.x, ub.y, ub.z, ub.w};
          const unsigned int pp[8] = {pa.x, pa.y, pa.z, pa.w, pb.x, pb.y, pb.z, pb.w};
          float sacc = 0.f;
#pragma unroll
          for (int i = 0; i < 8; ++i) {
            const h2f16 xs = __builtin_bit_cast(h2f16, uu[i]) + __builtin_bit_cast(h2f16, pp[i]);
            const h2f16 vv = __builtin_bit_cast(h2f16, v2p[i]);
            sacc += (float)vv.x * RCPF(1.f + EXP2F((float)xs.x));
            sacc += (float)vv.y * RCPF(1.f + EXP2F((float)xs.y));
          }
          sacc = redsum8dpp(sacc);
          if (sub == 0) sc[j * 128 + d8] = sacc;
        }
      }
      __syncthreads();  // B2

      // P4: redundant per-wave softmax + y_tilde; gates from regs; local LSTM
      float rden4[kGRP];
      {
        float yt4[kGRP];
#pragma unroll
        for (int j = 0; j < kGRP; ++j) {
          const float e0v = EXP2F(sc[j * 128 + lane] * kLog2e);
          float e1v = 0.f, x1 = 0.f;
          if (lane < 63) {
            e1v = EXP2F(sc[j * 128 + 64 + lane] * kLog2e);
            x1 = XW[j * 128 + 64 + lane];
          }
          float num = e0v * XW[j * 128 + lane] + e1v * x1;
          float den = e0v + e1v;
          num = redsum64dpp(num);
          den = redsum64dpp(den);
          rden4[j] = RCPF(den);
          yt4[j] = num * rden4[j] + yc[j * 128 + s];
        }
#pragma unroll
        for (int j = 0; j < kGRP; ++j) {
          const float gi = ga[j * 4 + 0] + bi4[0] + yt4[j] * wi4[0];
          const float gf = ga[j * 4 + 1] + bi4[1] + yt4[j] * wi4[1];
          const float gg = ga[j * 4 + 2] + bi4[2] + yt4[j] * wi4[2];
          const float go = ga[j * 4 + 3] + bi4[3] + yt4[j] * wi4[3];
          const float si = RCPF(1.f + EXP2F(-gi * kLog2e));
          const float sf = RCPF(1.f + EXP2F(-gf * kLog2e));
          const float tg = 1.f - 2.f * RCPF(1.f + EXP2F(gg * kK2));
          const float so = RCPF(1.f + EXP2F(-go * kLog2e));
          const float cn = sf * creg[j] + si * tg;
          creg[j] = cn;
          const float th = 1.f - 2.f * RCPF(1.f + EXP2F(cn * kK2));
          const float hn = so * th;
          const float ho = dppmov<0x128>(hn);   // partner lane^8 -> row d8^1
          const float co = dppmov<0x128>(cn);
          if ((tid & 15) == 0) {
            const int p = d8 >> 1;
            hc2[j * 160 + (p >> 4) * 20 + (p & 15)] = packf16(hn, ho);
            hc2[j * 160 + (4 + (p >> 4)) * 20 + (p & 15)] = packf16(cn, co);
          }
          if (s == kT - 1 && sub == 0) hl[j * 128 + d8] = hn;
        }
      }
      if (s == kT - 1 && tid < 512) {
        const int j = tid >> 7, t2 = tid & 127;
        const float rd = (j == 0) ? rden4[0] : (j == 1) ? rden4[1]
                       : (j == 2) ? rden4[2] : rden4[3];
        beta[tid] = (t2 < kT) ? EXP2F(sc[tid] * kLog2e) * rd : 0.f;
      }
      __syncthreads();  // B3
    }  // steps

    // ---- final ctx in fp32 from global X; then fc (4 outputs) ----
    {
      const int j = tid >> 8, r = tid & 255, e = r >> 1, hf = r & 1;
      const float* Xbj = Xg + (size_t)(b0 + j) * (kT * kE);
      float cacc = 0.f;
#pragma unroll
      for (int i = 0; i < 64; ++i) {
        const int t2 = hf * 64 + i;
        if (t2 < kT) cacc += beta[j * 128 + t2] * Xbj[(size_t)t2 * kE + e];
      }
      cacc += __shfl_xor(cacc, 1, 64);
      if (hf == 0) ctxl[j * 128 + e] = cacc;
    }
    __syncthreads();
    if (tid < 256) {
      const int j = tid >> 6, l = tid & 63;
      float a2 = hl[j * 128 + l] * fcw[l] + hl[j * 128 + 64 + l] * fcw[64 + l]
               + ctxl[j * 128 + l] * fcw[128 + l] + ctxl[j * 128 + 64 + l] * fcw[192 + l];
      a2 = redsum64(a2);
      if (l == 0) out[b0 + j] = a2 + fcb[0];
    }
  }  // group loop
}
}  // namespace

extern "C" void kernel_launch(void* const* d_in, const int* in_sizes, int n_in,
                              void* d_out, int out_size, void* d_ws, size_t ws_size,
                              hipStream_t stream) {
  (void)in_sizes; (void)n_in; (void)d_ws; (void)ws_size; (void)out_size;
  const float* Xg    = (const float*)d_in[0];
  const float* yh    = (const float*)d_in[1];
  const float* vdw   = (const float*)d_in[2];
  const float* vdb   = (const float*)d_in[3];
  const float* Wdhs  = (const float*)d_in[4];
  const float* Wdhsb = (const float*)d_in[5];
  const float* Udw   = (const float*)d_in[6];
  const float* Udb   = (const float*)d_in[7];
  const float* ww    = (const float*)d_in[8];
  const float* wb    = (const float*)d_in[9];
  const float* Wih   = (const float*)d_in[10];
  const float* Whh   = (const float*)d_in[11];
  const float* bih   = (const float*)d_in[12];
  const float* bhh   = (const float*)d_in[13];
  const float* fcww  = (const float*)d_in[14];
  const float* fcb   = (const float*)d_in[15];
  float* out = (float*)d_out;

  hipFuncSetAttribute((const void*)decoder_kernel,
                      hipFuncAttributeMaxDynamicSharedMemorySize, kSmemBytes);
  decoder_kernel<<<dim3(kNWG), dim3(1024), kSmemBytes, stream>>>(
      Xg, yh, vdw, vdb, Wdhs, Wdhsb, Udw, Udb, ww, wb,
      Wih, Whh, bih, bhh, fcww, fcb, out);
}

// Round 12
// 5634.710 us; speedup vs baseline: 1.5646x; 1.5646x over previous
//
#include <hip/hip_runtime.h>
#include <hip/hip_bf16.h>

#if __has_builtin(__builtin_amdgcn_exp2f)
#define EXP2F(x) __builtin_amdgcn_exp2f(x)
#else
#define EXP2F(x) exp2f(x)
#endif
#if __has_builtin(__builtin_amdgcn_rcpf)
#define RCPF(x) __builtin_amdgcn_rcpf(x)
#else
#define RCPF(x) (1.0f/(x))
#endif

typedef _Float16 h2f16 __attribute__((ext_vector_type(2)));

namespace {
constexpr int   kT   = 127;
constexpr int   kE   = 128;
constexpr int   kB   = 4096;
constexpr int   kNWG = 256;
constexpr int   kGRP = 4;                  // batches processed simultaneously
constexpr int   kBPW = 16;                 // batches per workgroup (4 groups)
constexpr float kLog2e = 1.4426950408889634f;
constexpr float kK2    = 2.8853900817779268f;   // 2*log2(e)
// u32: u2u 32768 + p2h 256 + hc2 512 ; f32: 6*512 + 128 + 256 + 132
constexpr int   kSmemBytes = (32768 + 256 + 512 + 6 * 512 + 128 + 256 + 132) * 4;

__device__ __forceinline__ unsigned int packf16(float a, float b) {
  h2f16 h = { (_Float16)a, (_Float16)b };
  return __builtin_bit_cast(unsigned int, h);
}

#if __has_builtin(__builtin_amdgcn_fdot2)
__device__ __forceinline__ float fdot2f(unsigned int a, unsigned int b, float c) {
  return __builtin_amdgcn_fdot2(__builtin_bit_cast(h2f16, a),
                                __builtin_bit_cast(h2f16, b), c, false);
}
#else
__device__ __forceinline__ float fdot2f(unsigned int a, unsigned int b, float c) {
  h2f16 ha = __builtin_bit_cast(h2f16, a), hb = __builtin_bit_cast(h2f16, b);
  return c + (float)ha.x * (float)hb.x + (float)ha.y * (float)hb.y;
}
#endif

// ---- DPP cross-lane (VALU pipe). ONLY direction-symmetric / explicit-perm
// controls are used: 0xB1 (quad_perm xor1), 0x4E (quad_perm xor2),
// 0x141 (row_half_mirror), 0x128 (row_ror:8 — symmetric: (i±8) mod 16 equal).
// Asymmetric ror:2/4/6 gathers were the r10/r11 bug (AMD ror is i <- i-N).
template <int CTRL>
__device__ __forceinline__ float dppadd(float x) {
  return x + __int_as_float(__builtin_amdgcn_update_dpp(
      0, __float_as_int(x), CTRL, 0xF, 0xF, true));
}
template <int CTRL>
__device__ __forceinline__ float dppmov(float x) {
  return __int_as_float(__builtin_amdgcn_update_dpp(
      0, __float_as_int(x), CTRL, 0xF, 0xF, true));
}
__device__ __forceinline__ float redsum8dpp(float x) {   // sum over lane bits 0..2
  x = dppadd<0xB1>(x); x = dppadd<0x4E>(x); x = dppadd<0x141>(x);
  return x;
}
__device__ __forceinline__ float redsum64dpp(float x) {  // full-wave sum (4 DPP + 2 shfl)
  x = dppadd<0xB1>(x); x = dppadd<0x4E>(x); x = dppadd<0x141>(x); x = dppadd<0x128>(x);
  x += __shfl_xor(x, 16, 64);
  x += __shfl_xor(x, 32, 64);
  return x;
}
__device__ __forceinline__ float redsum64(float a) {
#pragma unroll
  for (int m = 1; m < 64; m <<= 1) a += __shfl_xor(a, m, 64);
  return a;
}

// 1024 threads, 16 waves, 4 batches per step-group, 3 barriers/step.
// d8 = tid>>3 (0..127); sub = tid&7; gate = sub>>1 (i,f,g,o); khalf = sub&1.
__global__ __launch_bounds__(1024, 4) void decoder_kernel(
    const float* __restrict__ Xg,    // [B,127,128]
    const float* __restrict__ yh,    // [B,127]
    const float* __restrict__ vdw,   // [128]
    const float* __restrict__ vdb,   // [1]
    const float* __restrict__ Wdhs,  // [128,256]
    const float* __restrict__ Wdhsb, // [128]
    const float* __restrict__ Udw,   // [128,128]
    const float* __restrict__ Udb,   // [128]
    const float* __restrict__ ww,    // [129]
    const float* __restrict__ wb,    // [1]
    const float* __restrict__ Wih,   // [512]
    const float* __restrict__ Whh,   // [512,128]
    const float* __restrict__ bih,   // [512]
    const float* __restrict__ bhh,   // [512]
    const float* __restrict__ fcww,  // [256]
    const float* __restrict__ fcb,   // [1]
    float* __restrict__ out)         // [B]
{
  extern __shared__ char smem[];
  unsigned int* u2u  = (unsigned int*)smem;   // [4][128][64] f16 pairs; chunk c at c^(row&15)
  unsigned int* udw2 = u2u + 3 * 8192;        // staging scratch overlay on slot j=3
  unsigned int* p2h  = u2u + 4 * 8192;        // [4][64] f16 pairs of K2*(proj+b)
  unsigned int* hc2  = p2h + 256;             // [4][128]: h-pairs[0..64), c-pairs[64..128)
  float* sc   = (float*)(hc2 + 512);  // [4][128] raw scores
  float* XW   = sc   + 512;           // [4][128] ww . X[t,:]
  float* yc   = XW   + 512;           // [4][128] ww[128]*y + wb
  float* beta = yc   + 512;           // [4][128] softmax (last step only)
  float* hl   = beta + 512;           // [4][128] final h
  float* ctxl = hl   + 512;           // [4][128] final ctx
  float* udbl = ctxl + 512;           // [128]
  float* fcw  = udbl + 128;           // [256]
  float* wwl  = fcw  + 256;           // [132]

  const int tid   = threadIdx.x;
  const int d8    = tid >> 3;         // 0..127
  const int sub   = tid & 7;
  const int gate  = sub >> 1;         // 0:i 1:f 2:g 3:o
  const int khalf = sub & 1;
  const int g     = gate * 128 + d8;
  const int lane  = tid & 63;

  // ---- pinned per-thread weights: ~62 persistent values (proven-safe zone) ----
  unsigned int whh2[32];              // gate row g, K in [khalf*64, +64)
#pragma unroll
  for (int p = 0; p < 32; ++p)
    whh2[p] = packf16(Whh[g * 128 + khalf * 64 + 2 * p],
                      Whh[g * 128 + khalf * 64 + 2 * p + 1]);
  unsigned int wdq[16];               // proj row d8, K in [sub*32, +32) of concat(h,c)
#pragma unroll
  for (int q = 0; q < 16; ++q)
    wdq[q] = packf16(Wdhs[d8 * 256 + sub * 32 + 2 * q],
                     Wdhs[d8 * 256 + sub * 32 + 2 * q + 1]);
  unsigned int v2p[8];                // -2*v_d, e in [sub*16,+16), f16 pairs
#pragma unroll
  for (int i = 0; i < 8; ++i)
    v2p[i] = packf16(-2.0f * vdw[sub * 16 + 2 * i], -2.0f * vdw[sub * 16 + 2 * i + 1]);
  float bihh = bih[g] + bhh[g];
  float wihr = Wih[g];
  float wdbp = Wdhsb[d8];
  const float a_c = (gate == 2) ? -2.0f : 1.0f;
  const float b_c = (gate == 2) ? kK2 : -kLog2e;
  const float c_c = (gate == 2) ? 1.0f : 0.0f;
#pragma unroll
  for (int p = 0; p < 32; ++p) asm volatile("" : "+v"(whh2[p]));
#pragma unroll
  for (int q = 0; q < 16; ++q) asm volatile("" : "+v"(wdq[q]));
#pragma unroll
  for (int i = 0; i < 8; ++i) asm volatile("" : "+v"(v2p[i]));
  asm volatile("" : "+v"(bihh));
  asm volatile("" : "+v"(wihr));
  asm volatile("" : "+v"(wdbp));

  // ---- one-time constants ----
  if (tid < 132) wwl[tid] = (tid < 129) ? ww[tid] : ((tid == 129) ? wb[0] : 0.f);
  if (tid < 256) fcw[tid] = fcww[tid];
  if (tid < 128) udbl[tid] = Udb[tid];
  (void)vdb;   // constant shift, cancels in softmax

  for (int grp = 0; grp < kBPW / kGRP; ++grp) {
    const int b0 = blockIdx.x * kBPW + grp * kGRP;
    float creg[kGRP] = {0.f, 0.f, 0.f, 0.f};
    __syncthreads();   // previous group done with LDS

    // ---- S1: stage Udw f16 (swizzled) into slot3 scratch + init state/yc/XW pad ----
    {
      const int r = tid >> 3, mb = (tid & 7) * 2;
#pragma unroll
      for (int ch = 0; ch < 2; ++ch) {
        const int m = mb + ch;
        const float4 wa = *(const float4*)&Udw[r * kE + m * 8];
        const float4 wb4 = *(const float4*)&Udw[r * kE + m * 8 + 4];
        uint4 st;
        st.x = packf16(wa.x, wa.y);  st.y = packf16(wa.z, wa.w);
        st.z = packf16(wb4.x, wb4.y); st.w = packf16(wb4.z, wb4.w);
        *(uint4*)&udw2[r * 64 + ((m ^ (r >> 4)) << 2)] = st;
      }
    }
    if (tid < 512) {
      const int j = tid >> 7, s2 = tid & 127;
      hc2[tid] = 0u;
      yc[tid] = (s2 < kT) ? wwl[128] * yh[(size_t)(b0 + j) * kT + s2] + wwl[129] : 0.f;
      if (s2 == 127) XW[tid] = 0.f;
    }
    __syncthreads();

    // ---- S2: U2 = K2*(X @ Udw^T + Udb) (f16, swizzled) + XW, 4 batches ----
    uint4 st3a, st3b;
    if (d8 < kT) {
#pragma unroll
      for (int j = 0; j < kGRP; ++j) {
        const float* Xrow = Xg + (size_t)(b0 + j) * (kT * kE) + d8 * kE;
        float a = 0.f;
#pragma unroll
        for (int q = 0; q < 4; ++q) {
          const float4 xv = *(const float4*)&Xrow[sub * 16 + q * 4];
          const float4 wv = *(const float4*)&wwl[sub * 16 + q * 4];
          a += xv.x * wv.x + xv.y * wv.y + xv.z * wv.z + xv.w * wv.w;
        }
        a = redsum8dpp(a);
        if (sub == 0) XW[j * 128 + d8] = a;
        float acc[16];
#pragma unroll
        for (int jj = 0; jj < 16; ++jj) acc[jj] = 0.f;
        for (int m = 0; m < 16; ++m) {
          const float4 xa = *(const float4*)&Xrow[m * 8];
          const float4 xb4 = *(const float4*)&Xrow[m * 8 + 4];
          const unsigned int xp0 = packf16(xa.x, xa.y), xp1 = packf16(xa.z, xa.w);
          const unsigned int xp2 = packf16(xb4.x, xb4.y), xp3 = packf16(xb4.z, xb4.w);
#pragma unroll
          for (int jj = 0; jj < 16; ++jj) {
            const uint4 wq = *(const uint4*)&udw2[(sub * 16 + jj) * 64 + ((m ^ sub) << 2)];
            acc[jj] = fdot2f(xp3, wq.w, fdot2f(xp2, wq.z,
                      fdot2f(xp1, wq.y, fdot2f(xp0, wq.x, acc[jj]))));
          }
        }
        uint4 s0, s1;
        const int eb = sub * 16;
        s0.x = packf16(kK2 * (acc[0] + udbl[eb + 0]), kK2 * (acc[1] + udbl[eb + 1]));
        s0.y = packf16(kK2 * (acc[2] + udbl[eb + 2]), kK2 * (acc[3] + udbl[eb + 3]));
        s0.z = packf16(kK2 * (acc[4] + udbl[eb + 4]), kK2 * (acc[5] + udbl[eb + 5]));
        s0.w = packf16(kK2 * (acc[6] + udbl[eb + 6]), kK2 * (acc[7] + udbl[eb + 7]));
        s1.x = packf16(kK2 * (acc[8] + udbl[eb + 8]), kK2 * (acc[9] + udbl[eb + 9]));
        s1.y = packf16(kK2 * (acc[10] + udbl[eb + 10]), kK2 * (acc[11] + udbl[eb + 11]));
        s1.z = packf16(kK2 * (acc[12] + udbl[eb + 12]), kK2 * (acc[13] + udbl[eb + 13]));
        s1.w = packf16(kK2 * (acc[14] + udbl[eb + 14]), kK2 * (acc[15] + udbl[eb + 15]));
        if (j < 3) {
          *(uint4*)&u2u[j * 8192 + d8 * 64 + (((sub * 2 + 0) ^ (d8 & 15)) << 2)] = s0;
          *(uint4*)&u2u[j * 8192 + d8 * 64 + (((sub * 2 + 1) ^ (d8 & 15)) << 2)] = s1;
        } else { st3a = s0; st3b = s1; }
      }
    }
    __syncthreads();   // udw2 fully consumed
    if (d8 < kT) {
      *(uint4*)&u2u[3 * 8192 + d8 * 64 + (((sub * 2 + 0) ^ (d8 & 15)) << 2)] = st3a;
      *(uint4*)&u2u[3 * 8192 + d8 * 64 + (((sub * 2 + 1) ^ (d8 & 15)) << 2)] = st3b;
    }
    // (slot-3 stores separated from first read by B1 in the step loop)

    // ================= 127 steps x 4 batches, 3 barriers each =================
    for (int s = 0; s < kT; ++s) {
      // P1: gate row (xor1 pair-combine via quad_perm, kept in regs all step);
      //     proj row -> p2h f16 pairs (DPP 8-lane reduce + symmetric ror:8 pack).
      float gc[kGRP];
#pragma unroll
      for (int j = 0; j < kGRP; ++j) {
        const unsigned int* hj = hc2 + j * 128;
        float ga = 0.f;
#pragma unroll
        for (int q = 0; q < 8; ++q) {
          const uint4 h4 = *(const uint4*)&hj[khalf * 32 + q * 4];
          ga = fdot2f(whh2[q * 4 + 0], h4.x, ga);
          ga = fdot2f(whh2[q * 4 + 1], h4.y, ga);
          ga = fdot2f(whh2[q * 4 + 2], h4.z, ga);
          ga = fdot2f(whh2[q * 4 + 3], h4.w, ga);
        }
        gc[j] = dppadd<0xB1>(ga);        // xor1: combine K-halves, both pair lanes hold gate sum
        float pp = 0.f;
#pragma unroll
        for (int q = 0; q < 4; ++q) {
          const uint4 h4 = *(const uint4*)&hj[sub * 16 + q * 4];
          pp = fdot2f(wdq[q * 4 + 0], h4.x, pp);
          pp = fdot2f(wdq[q * 4 + 1], h4.y, pp);
          pp = fdot2f(wdq[q * 4 + 2], h4.z, pp);
          pp = fdot2f(wdq[q * 4 + 3], h4.w, pp);
        }
        pp = redsum8dpp(pp);
        const float pv = kK2 * (pp + wdbp);
        const float pvo = dppmov<0x128>(pv);    // partner row d8^1 (ror:8, symmetric)
        if ((tid & 15) == 0) p2h[j * 64 + (d8 >> 1)] = packf16(pv, pvo);
      }
      __syncthreads();  // B1

      // P3: score row d8, e-chunk [sub*16,+16) — r8-validated numerics:
      //     f16 packed add (u+p), f32 exp/rcp sigmoid, f32 accumulate.
      if (d8 < kT) {
        const int sw = d8 & 15;
#pragma unroll
        for (int j = 0; j < kGRP; ++j) {
          const unsigned int* ur = u2u + j * 8192 + d8 * 64;
          const unsigned int* ph = p2h + j * 64;
          const uint4 ua = *(const uint4*)&ur[(((sub * 2 + 0) ^ sw) << 2)];
          const uint4 ub = *(const uint4*)&ur[(((sub * 2 + 1) ^ sw) << 2)];
          const uint4 pa = *(const uint4*)&ph[sub * 8];
          const uint4 pb = *(const uint4*)&ph[sub * 8 + 4];
          const unsigned int uu[8] = {ua.x, ua.y, ua.z, ua.w, ub.x, ub.y, ub.z, ub.w};
          const unsigned int pp[8] = {pa.x, pa.y, pa.z, pa.w, pb.x, pb.y, pb.z, pb.w};
          float sacc = 0.f;
#pragma unroll
          for (int i = 0; i < 8; ++i) {
            const h2f16 xs = __builtin_bit_cast(h2f16, uu[i])
                           + __builtin_bit_cast(h2f16, pp[i]);
            const h2f16 vv = __builtin_bit_cast(h2f16, v2p[i]);
            sacc += (float)vv.x * RCPF(1.f + EXP2F((float)xs.x));
            sacc += (float)vv.y * RCPF(1.f + EXP2F((float)xs.y));
          }
          sacc = redsum8dpp(sacc);
          if (sub == 0) sc[j * 128 + d8] = sacc;
        }
      }
      __syncthreads();  // B2

      // P4: redundant per-wave softmax + y_tilde (DPP butterfly + 2 shfl);
      //     gate gather via shfl_xor 2/4/6 (r7-validated; NOT asymmetric ror).
      float rden4[kGRP];
      {
        float yt4[kGRP];
#pragma unroll
        for (int j = 0; j < kGRP; ++j) {
          const float e0v = EXP2F(sc[j * 128 + lane] * kLog2e);
          float e1v = 0.f, x1 = 0.f;
          if (lane < 63) {
            e1v = EXP2F(sc[j * 128 + 64 + lane] * kLog2e);
            x1 = XW[j * 128 + 64 + lane];
          }
          float num = e0v * XW[j * 128 + lane] + e1v * x1;
          float den = e0v + e1v;
          num = redsum64dpp(num);
          den = redsum64dpp(den);
          rden4[j] = RCPF(den);
          yt4[j] = num * rden4[j] + yc[j * 128 + s];
        }
#pragma unroll
        for (int j = 0; j < kGRP; ++j) {
          const float av = c_c + a_c * RCPF(1.f + EXP2F(b_c * (gc[j] + bihh + yt4[j] * wihr)));
          const float fv = __shfl_xor(av, 2, 64);   // f gate (xor2)
          const float gv = __shfl_xor(av, 4, 64);   // g gate (xor4)
          const float ov = __shfl_xor(av, 6, 64);   // o gate (xor6)
          const float cn = fv * creg[j] + av * gv;  // valid on sub==0 (and 1)
          creg[j] = cn;
          const float th = 1.f - 2.f * RCPF(1.f + EXP2F(cn * kK2));
          const float hn = ov * th;
          const float ho = dppmov<0x128>(hn);   // partner row d8^1 (symmetric)
          const float co = dppmov<0x128>(cn);
          if ((tid & 15) == 0) {
            hc2[j * 128 + (d8 >> 1)]      = packf16(hn, ho);
            hc2[j * 128 + 64 + (d8 >> 1)] = packf16(cn, co);
          }
          if (s == kT - 1 && sub == 0) hl[j * 128 + d8] = hn;
        }
      }
      if (s == kT - 1 && tid < 512) {
        const int j = tid >> 7, t2 = tid & 127;
        const float rd = (j == 0) ? rden4[0] : (j == 1) ? rden4[1]
                       : (j == 2) ? rden4[2] : rden4[3];
        beta[tid] = (t2 < kT) ? EXP2F(sc[tid] * kLog2e) * rd : 0.f;
      }
      __syncthreads();  // B3
    }  // steps

    // ---- final ctx in fp32 from global X; then fc (4 outputs) ----
    {
      const int j = tid >> 8, r = tid & 255, e = r >> 1, hf = r & 1;
      const float* Xbj = Xg + (size_t)(b0 + j) * (kT * kE);
      float cacc = 0.f;
#pragma unroll
      for (int i = 0; i < 64; ++i) {
        const int t2 = hf * 64 + i;
        if (t2 < kT) cacc += beta[j * 128 + t2] * Xbj[(size_t)t2 * kE + e];
      }
      cacc += __shfl_xor(cacc, 1, 64);
      if (hf == 0) ctxl[j * 128 + e] = cacc;
    }
    __syncthreads();
    if (tid < 256) {
      const int j = tid >> 6, l = tid & 63;
      float a2 = hl[j * 128 + l] * fcw[l] + hl[j * 128 + 64 + l] * fcw[64 + l]
               + ctxl[j * 128 + l] * fcw[128 + l] + ctxl[j * 128 + 64 + l] * fcw[192 + l];
      a2 = redsum64(a2);
      if (l == 0) out[b0 + j] = a2 + fcb[0];
    }
  }  // group loop
}
}  // namespace

extern "C" void kernel_launch(void* const* d_in, const int* in_sizes, int n_in,
                              void* d_out, int out_size, void* d_ws, size_t ws_size,
                              hipStream_t stream) {
  (void)in_sizes; (void)n_in; (void)d_ws; (void)ws_size; (void)out_size;
  const float* Xg    = (const float*)d_in[0];
  const float* yh    = (const float*)d_in[1];
  const float* vdw   = (const float*)d_in[2];
  const float* vdb   = (const float*)d_in[3];
  const float* Wdhs  = (const float*)d_in[4];
  const float* Wdhsb = (const float*)d_in[5];
  const float* Udw   = (const float*)d_in[6];
  const float* Udb   = (const float*)d_in[7];
  const float* ww    = (const float*)d_in[8];
  const float* wb    = (const float*)d_in[9];
  const float* Wih   = (const float*)d_in[10];
  const float* Whh   = (const float*)d_in[11];
  const float* bih   = (const float*)d_in[12];
  const float* bhh   = (const float*)d_in[13];
  const float* fcww  = (const float*)d_in[14];
  const float* fcb   = (const float*)d_in[15];
  float* out = (float*)d_out;

  hipFuncSetAttribute((const void*)decoder_kernel,
                      hipFuncAttributeMaxDynamicSharedMemorySize, kSmemBytes);
  decoder_kernel<<<dim3(kNWG), dim3(1024), kSmemBytes, stream>>>(
      Xg, yh, vdw, vdb, Wdhs, Wdhsb, Udw, Udb, ww, wb,
      Wih, Whh, bih, bhh, fcww, fcb, out);
}

// Round 13
// 4724.324 us; speedup vs baseline: 1.8661x; 1.1927x over previous
//
#include <hip/hip_runtime.h>
#include <hip/hip_bf16.h>

#if __has_builtin(__builtin_amdgcn_exp2f)
#define EXP2F(x) __builtin_amdgcn_exp2f(x)
#else
#define EXP2F(x) exp2f(x)
#endif
#if __has_builtin(__builtin_amdgcn_rcpf)
#define RCPF(x) __builtin_amdgcn_rcpf(x)
#else
#define RCPF(x) (1.0f/(x))
#endif

typedef _Float16 h2f16 __attribute__((ext_vector_type(2)));
typedef _Float16 f16x8 __attribute__((ext_vector_type(8)));
typedef float    f32x16 __attribute__((ext_vector_type(16)));

namespace {
constexpr int   kT   = 127;
constexpr int   kE   = 128;
constexpr int   kB   = 4096;
constexpr int   kNWG = 256;
constexpr int   kGRP = 4;                  // batches processed simultaneously
constexpr int   kBPW = 16;                 // batches per workgroup (4 groups)
constexpr float kLog2e = 1.4426950408889634f;
constexpr float kK2    = 2.8853900817779268f;   // 2*log2(e)
// u32: u2u 32768 + p2h 256 + hc2 672 ; f32: act 2064 + 6*512 + 128 + 256 + 132
constexpr int   kSmemBytes = (32768 + 256 + 672) * 4 + (2064 + 6 * 512 + 128 + 256 + 132) * 4;

__device__ __forceinline__ unsigned int packf16(float a, float b) {
  h2f16 h = { (_Float16)a, (_Float16)b };
  return __builtin_bit_cast(unsigned int, h);
}

#if __has_builtin(__builtin_amdgcn_fdot2)
__device__ __forceinline__ float fdot2f(unsigned int a, unsigned int b, float c) {
  return __builtin_amdgcn_fdot2(__builtin_bit_cast(h2f16, a),
                                __builtin_bit_cast(h2f16, b), c, false);
}
#else
__device__ __forceinline__ float fdot2f(unsigned int a, unsigned int b, float c) {
  h2f16 ha = __builtin_bit_cast(h2f16, a), hb = __builtin_bit_cast(h2f16, b);
  return c + (float)ha.x * (float)hb.x + (float)ha.y * (float)hb.y;
}
#endif

// ---- DPP cross-lane (direction-symmetric controls only; r12-validated) ----
template <int CTRL>
__device__ __forceinline__ float dppadd(float x) {
  return x + __int_as_float(__builtin_amdgcn_update_dpp(
      0, __float_as_int(x), CTRL, 0xF, 0xF, true));
}
template <int CTRL>
__device__ __forceinline__ float dppmov(float x) {
  return __int_as_float(__builtin_amdgcn_update_dpp(
      0, __float_as_int(x), CTRL, 0xF, 0xF, true));
}
__device__ __forceinline__ float redsum8dpp(float x) {   // sum over lane bits 0..2
  x = dppadd<0xB1>(x); x = dppadd<0x4E>(x); x = dppadd<0x141>(x);
  return x;
}
__device__ __forceinline__ float redsum64dpp(float x) {  // full-wave sum (4 DPP + 2 shfl)
  x = dppadd<0xB1>(x); x = dppadd<0x4E>(x); x = dppadd<0x141>(x); x = dppadd<0x128>(x);
  x += __shfl_xor(x, 16, 64);
  x += __shfl_xor(x, 32, 64);
  return x;
}
__device__ __forceinline__ float redsum64(float a) {
#pragma unroll
  for (int m = 1; m < 64; m <<= 1) a += __shfl_xor(a, m, 64);
  return a;
}

// 1024 threads, 16 waves, 4 batches per step-group, 3 barriers/step.
// d8 = tid>>3 (0..127); sub = tid&7; gate = sub>>1 (i,f,g,o); khalf = sub&1.
// Gate GEMV runs on MFMA: wave wid owns 32x32 tile of row-interleaved Whh
// (row' = d*4 + gate), batches in N-dim; pre-activations to act[] LDS.
__global__ __launch_bounds__(1024, 4) void decoder_kernel(
    const float* __restrict__ Xg,    // [B,127,128]
    const float* __restrict__ yh,    // [B,127]
    const float* __restrict__ vdw,   // [128]
    const float* __restrict__ vdb,   // [1]
    const float* __restrict__ Wdhs,  // [128,256]
    const float* __restrict__ Wdhsb, // [128]
    const float* __restrict__ Udw,   // [128,128]
    const float* __restrict__ Udb,   // [128]
    const float* __restrict__ ww,    // [129]
    const float* __restrict__ wb,    // [1]
    const float* __restrict__ Wih,   // [512]
    const float* __restrict__ Whh,   // [512,128]
    const float* __restrict__ bih,   // [512]
    const float* __restrict__ bhh,   // [512]
    const float* __restrict__ fcww,  // [256]
    const float* __restrict__ fcb,   // [1]
    float* __restrict__ out)         // [B]
{
  extern __shared__ char smem[];
  unsigned int* u2u  = (unsigned int*)smem;   // [4][128][64] f16 pairs; chunk c at c^(row&15)
  unsigned int* udw2 = u2u + 3 * 8192;        // staging scratch overlay on slot j=3
  unsigned int* p2h  = u2u + 4 * 8192;        // [4][64] f16 pairs of K2*(proj+b)
  unsigned int* hc2  = p2h + 256;             // [4][168]: 8 chunks of 16 u32 + 4 pad (20-stride);
                                              //   chunks 0-3 = h-pairs, 4-7 = c-pairs
  float* act  = (float*)(hc2 + 672);  // [4][516] gate pre-activations, row' = d*4+gate
  float* sc   = act  + 2064;          // [4][128] raw scores
  float* XW   = sc   + 512;           // [4][128] ww . X[t,:]
  float* yc   = XW   + 512;           // [4][128] ww[128]*y + wb
  float* beta = yc   + 512;           // [4][128] softmax (last step only)
  float* hl   = beta + 512;           // [4][128] final h
  float* ctxl = hl   + 512;           // [4][128] final ctx
  float* udbl = ctxl + 512;           // [128]
  float* fcw  = udbl + 128;           // [256]
  float* wwl  = fcw  + 256;           // [132]

  const int tid   = threadIdx.x;
  const int d8    = tid >> 3;         // 0..127
  const int sub   = tid & 7;
  const int gate  = sub >> 1;         // 0:i 1:f 2:g 3:o
  const int g     = gate * 128 + d8;
  const int lane  = tid & 63;

  // ---- pinned per-thread weights: ~62 persistent values ----
  // whhA: MFMA A-fragments. Wave wid owns tile rows' [32*wid, +32);
  // lane l: row' = 32*wid + (l&31) -> d = 8*wid + ((l&31)>>2), gate = l&3;
  // k = kk*16 + (l>>5)*8 + i  (same k-formula used for B -> permutation cancels).
  unsigned int whhA[32];
  {
    const int wid = tid >> 6;
    const int rrA = lane & 31;
    const int rowA = (rrA & 3) * 128 + (8 * wid + (rrA >> 2));  // gate*128 + d
    const int kbA = (lane >> 5) * 8;
#pragma unroll
    for (int kk = 0; kk < 8; ++kk)
#pragma unroll
      for (int i2 = 0; i2 < 4; ++i2) {
        const int k = kk * 16 + kbA + 2 * i2;
        whhA[kk * 4 + i2] = packf16(Whh[rowA * 128 + k], Whh[rowA * 128 + k + 1]);
      }
  }
  unsigned int wdq[16];               // proj row d8, K in [sub*32, +32) of concat(h,c)
#pragma unroll
  for (int q = 0; q < 16; ++q)
    wdq[q] = packf16(Wdhs[d8 * 256 + sub * 32 + 2 * q],
                     Wdhs[d8 * 256 + sub * 32 + 2 * q + 1]);
  unsigned int v2p[8];                // -2*v_d, e in [sub*16,+16), f16 pairs
#pragma unroll
  for (int i = 0; i < 8; ++i)
    v2p[i] = packf16(-2.0f * vdw[sub * 16 + 2 * i], -2.0f * vdw[sub * 16 + 2 * i + 1]);
  float bihh = bih[g] + bhh[g];
  float wihr = Wih[g];
  float wdbp = Wdhsb[d8];
  const float a_c = (gate == 2) ? -2.0f : 1.0f;
  const float b_c = (gate == 2) ? kK2 : -kLog2e;
  const float c_c = (gate == 2) ? 1.0f : 0.0f;
#pragma unroll
  for (int p = 0; p < 32; ++p) asm volatile("" : "+v"(whhA[p]));
#pragma unroll
  for (int q = 0; q < 16; ++q) asm volatile("" : "+v"(wdq[q]));
#pragma unroll
  for (int i = 0; i < 8; ++i) asm volatile("" : "+v"(v2p[i]));
  asm volatile("" : "+v"(bihh));
  asm volatile("" : "+v"(wihr));
  asm volatile("" : "+v"(wdbp));

  // ---- one-time constants ----
  if (tid < 132) wwl[tid] = (tid < 129) ? ww[tid] : ((tid == 129) ? wb[0] : 0.f);
  if (tid < 256) fcw[tid] = fcww[tid];
  if (tid < 128) udbl[tid] = Udb[tid];
  (void)vdb;   // constant shift, cancels in softmax

  for (int grp = 0; grp < kBPW / kGRP; ++grp) {
    const int b0 = blockIdx.x * kBPW + grp * kGRP;
    float creg[kGRP] = {0.f, 0.f, 0.f, 0.f};
    __syncthreads();   // previous group done with LDS

    // ---- S1: stage Udw f16 (swizzled) into slot3 scratch + init state/yc/XW pad ----
    {
      const int r = tid >> 3, mb = (tid & 7) * 2;
#pragma unroll
      for (int ch = 0; ch < 2; ++ch) {
        const int m = mb + ch;
        const float4 wa = *(const float4*)&Udw[r * kE + m * 8];
        const float4 wb4 = *(const float4*)&Udw[r * kE + m * 8 + 4];
        uint4 st;
        st.x = packf16(wa.x, wa.y);  st.y = packf16(wa.z, wa.w);
        st.z = packf16(wb4.x, wb4.y); st.w = packf16(wb4.z, wb4.w);
        *(uint4*)&udw2[r * 64 + ((m ^ (r >> 4)) << 2)] = st;
      }
    }
    if (tid < 672) hc2[tid] = 0u;
    if (tid < 512) {
      const int j = tid >> 7, s2 = tid & 127;
      yc[tid] = (s2 < kT) ? wwl[128] * yh[(size_t)(b0 + j) * kT + s2] + wwl[129] : 0.f;
      if (s2 == 127) XW[tid] = 0.f;
    }
    __syncthreads();

    // ---- S2: U2 = K2*(X @ Udw^T + Udb) (f16, swizzled) + XW, 4 batches ----
    uint4 st3a, st3b;
    if (d8 < kT) {
#pragma unroll
      for (int j = 0; j < kGRP; ++j) {
        const float* Xrow = Xg + (size_t)(b0 + j) * (kT * kE) + d8 * kE;
        float a = 0.f;
#pragma unroll
        for (int q = 0; q < 4; ++q) {
          const float4 xv = *(const float4*)&Xrow[sub * 16 + q * 4];
          const float4 wv = *(const float4*)&wwl[sub * 16 + q * 4];
          a += xv.x * wv.x + xv.y * wv.y + xv.z * wv.z + xv.w * wv.w;
        }
        a = redsum8dpp(a);
        if (sub == 0) XW[j * 128 + d8] = a;
        float acc[16];
#pragma unroll
        for (int jj = 0; jj < 16; ++jj) acc[jj] = 0.f;
        for (int m = 0; m < 16; ++m) {
          const float4 xa = *(const float4*)&Xrow[m * 8];
          const float4 xb4 = *(const float4*)&Xrow[m * 8 + 4];
          const unsigned int xp0 = packf16(xa.x, xa.y), xp1 = packf16(xa.z, xa.w);
          const unsigned int xp2 = packf16(xb4.x, xb4.y), xp3 = packf16(xb4.z, xb4.w);
#pragma unroll
          for (int jj = 0; jj < 16; ++jj) {
            const uint4 wq = *(const uint4*)&udw2[(sub * 16 + jj) * 64 + ((m ^ sub) << 2)];
            acc[jj] = fdot2f(xp3, wq.w, fdot2f(xp2, wq.z,
                      fdot2f(xp1, wq.y, fdot2f(xp0, wq.x, acc[jj]))));
          }
        }
        uint4 s0, s1;
        const int eb = sub * 16;
        s0.x = packf16(kK2 * (acc[0] + udbl[eb + 0]), kK2 * (acc[1] + udbl[eb + 1]));
        s0.y = packf16(kK2 * (acc[2] + udbl[eb + 2]), kK2 * (acc[3] + udbl[eb + 3]));
        s0.z = packf16(kK2 * (acc[4] + udbl[eb + 4]), kK2 * (acc[5] + udbl[eb + 5]));
        s0.w = packf16(kK2 * (acc[6] + udbl[eb + 6]), kK2 * (acc[7] + udbl[eb + 7]));
        s1.x = packf16(kK2 * (acc[8] + udbl[eb + 8]), kK2 * (acc[9] + udbl[eb + 9]));
        s1.y = packf16(kK2 * (acc[10] + udbl[eb + 10]), kK2 * (acc[11] + udbl[eb + 11]));
        s1.z = packf16(kK2 * (acc[12] + udbl[eb + 12]), kK2 * (acc[13] + udbl[eb + 13]));
        s1.w = packf16(kK2 * (acc[14] + udbl[eb + 14]), kK2 * (acc[15] + udbl[eb + 15]));
        if (j < 3) {
          *(uint4*)&u2u[j * 8192 + d8 * 64 + (((sub * 2 + 0) ^ (d8 & 15)) << 2)] = s0;
          *(uint4*)&u2u[j * 8192 + d8 * 64 + (((sub * 2 + 1) ^ (d8 & 15)) << 2)] = s1;
        } else { st3a = s0; st3b = s1; }
      }
    }
    __syncthreads();   // udw2 fully consumed
    if (d8 < kT) {
      *(uint4*)&u2u[3 * 8192 + d8 * 64 + (((sub * 2 + 0) ^ (d8 & 15)) << 2)] = st3a;
      *(uint4*)&u2u[3 * 8192 + d8 * 64 + (((sub * 2 + 1) ^ (d8 & 15)) << 2)] = st3b;
    }
    // (slot-3 stores separated from first read by B1 in the step loop)

    // ================= 127 steps x 4 batches, 3 barriers each =================
    for (int s = 0; s < kT; ++s) {
      // P1a: gate GEMV on MFMA — one 32x32x16_f16 tile per wave over 8 K-frags;
      //      all 4 batches ride the N dimension. Pre-activations -> act[].
      {
        f32x16 macc;
#pragma unroll
        for (int i = 0; i < 16; ++i) macc[i] = 0.f;
        const int jn = tid & 3;                  // B col (batch), clamped pattern
        const int hi4 = ((tid >> 5) & 1) * 4;    // (lane>>5)*4
#pragma unroll
        for (int kk = 0; kk < 8; ++kk) {
          const int p0 = kk * 8 + hi4;           // h-pair base (8 consecutive k)
          const uint4 bq = *(const uint4*)&hc2[jn * 168 + (p0 >> 4) * 20 + (p0 & 15)];
          const uint4 aq = {whhA[kk * 4 + 0], whhA[kk * 4 + 1],
                            whhA[kk * 4 + 2], whhA[kk * 4 + 3]};
          macc = __builtin_amdgcn_mfma_f32_32x32x16_f16(
              __builtin_bit_cast(f16x8, aq), __builtin_bit_cast(f16x8, bq),
              macc, 0, 0, 0);
        }
        if ((tid & 31) < 4) {                    // valid batch columns only
          const int wid = tid >> 6;
#pragma unroll
          for (int qq = 0; qq < 4; ++qq) {
            float4 v = {macc[qq * 4 + 0], macc[qq * 4 + 1],
                        macc[qq * 4 + 2], macc[qq * 4 + 3]};
            // rows' = 32*wid + 8*qq + hi4 + (0..3)  [C layout: (reg&3)+8*(reg>>2)+4*(l>>5)]
            *(float4*)&act[(tid & 3) * 516 + 32 * wid + 8 * qq + hi4] = v;
          }
        }
      }
      // P1b: proj row -> p2h f16 pairs (DPP 8-lane reduce + symmetric ror:8 pack)
#pragma unroll
      for (int j = 0; j < kGRP; ++j) {
        const unsigned int* hj = hc2 + j * 168;
        float pp = 0.f;
#pragma unroll
        for (int q = 0; q < 4; ++q) {
          const uint4 h4 = *(const uint4*)&hj[sub * 20 + q * 4];
          pp = fdot2f(wdq[q * 4 + 0], h4.x, pp);
          pp = fdot2f(wdq[q * 4 + 1], h4.y, pp);
          pp = fdot2f(wdq[q * 4 + 2], h4.z, pp);
          pp = fdot2f(wdq[q * 4 + 3], h4.w, pp);
        }
        pp = redsum8dpp(pp);
        const float pv = kK2 * (pp + wdbp);
        const float pvo = dppmov<0x128>(pv);    // partner row d8^1 (ror:8, symmetric)
        if ((tid & 15) == 0) p2h[j * 64 + (d8 >> 1)] = packf16(pv, pvo);
      }
      __syncthreads();  // B1

      // P3: score row d8, e-chunk [sub*16,+16) — f16 packed add, f32 sigmoid
      if (d8 < kT) {
        const int sw = d8 & 15;
#pragma unroll
        for (int j = 0; j < kGRP; ++j) {
          const unsigned int* ur = u2u + j * 8192 + d8 * 64;
          const unsigned int* ph = p2h + j * 64;
          const uint4 ua = *(const uint4*)&ur[(((sub * 2 + 0) ^ sw) << 2)];
          const uint4 ub = *(const uint4*)&ur[(((sub * 2 + 1) ^ sw) << 2)];
          const uint4 pa = *(const uint4*)&ph[sub * 8];
          const uint4 pb = *(const uint4*)&ph[sub * 8 + 4];
          const unsigned int uu[8] = {ua.x, ua.y, ua.z, ua.w, ub.x, ub.y, ub.z, ub.w};
          const unsigned int pp[8] = {pa.x, pa.y, pa.z, pa.w, pb.x, pb.y, pb.z, pb.w};
          float sacc = 0.f;
#pragma unroll
          for (int i = 0; i < 8; ++i) {
            const h2f16 xs = __builtin_bit_cast(h2f16, uu[i])
                           + __builtin_bit_cast(h2f16, pp[i]);
            const h2f16 vv = __builtin_bit_cast(h2f16, v2p[i]);
            sacc += (float)vv.x * RCPF(1.f + EXP2F((float)xs.x));
            sacc += (float)vv.y * RCPF(1.f + EXP2F((float)xs.y));
          }
          sacc = redsum8dpp(sacc);
          if (sub == 0) sc[j * 128 + d8] = sacc;
        }
      }
      __syncthreads();  // B2

      // P4: redundant per-wave softmax + y_tilde; gates from act[]; lane-local LSTM
      float rden4[kGRP];
      {
        float yt4[kGRP];
#pragma unroll
        for (int j = 0; j < kGRP; ++j) {
          const float e0v = EXP2F(sc[j * 128 + lane] * kLog2e);
          float e1v = 0.f, x1 = 0.f;
          if (lane < 63) {
            e1v = EXP2F(sc[j * 128 + 64 + lane] * kLog2e);
            x1 = XW[j * 128 + 64 + lane];
          }
          float num = e0v * XW[j * 128 + lane] + e1v * x1;
          float den = e0v + e1v;
          num = redsum64dpp(num);
          den = redsum64dpp(den);
          rden4[j] = RCPF(den);
          yt4[j] = num * rden4[j] + yc[j * 128 + s];
        }
#pragma unroll
        for (int j = 0; j < kGRP; ++j) {
          const float gdot = act[j * 516 + (d8 << 2) + gate];   // own-gate pre-activation
          const float av = c_c + a_c * RCPF(1.f + EXP2F(b_c * (gdot + bihh + yt4[j] * wihr)));
          const float fv = __shfl_xor(av, 2, 64);   // f gate (xor2)
          const float gv = __shfl_xor(av, 4, 64);   // g gate (xor4)
          const float ov = __shfl_xor(av, 6, 64);   // o gate (xor6)
          const float cn = fv * creg[j] + av * gv;  // valid on sub==0 (and 1)
          creg[j] = cn;
          const float th = 1.f - 2.f * RCPF(1.f + EXP2F(cn * kK2));
          const float hn = ov * th;
          const float ho = dppmov<0x128>(hn);   // partner row d8^1 (symmetric)
          const float co = dppmov<0x128>(cn);
          if ((tid & 15) == 0) {
            const int p = d8 >> 1;
            hc2[j * 168 + ((p >> 4)) * 20 + (p & 15)]       = packf16(hn, ho);
            hc2[j * 168 + (4 + (p >> 4)) * 20 + (p & 15)]   = packf16(cn, co);
          }
          if (s == kT - 1 && sub == 0) hl[j * 128 + d8] = hn;
        }
      }
      if (s == kT - 1 && tid < 512) {
        const int j = tid >> 7, t2 = tid & 127;
        const float rd = (j == 0) ? rden4[0] : (j == 1) ? rden4[1]
                       : (j == 2) ? rden4[2] : rden4[3];
        beta[tid] = (t2 < kT) ? EXP2F(sc[tid] * kLog2e) * rd : 0.f;
      }
      __syncthreads();  // B3
    }  // steps

    // ---- final ctx in fp32 from global X; then fc (4 outputs) ----
    {
      const int j = tid >> 8, r = tid & 255, e = r >> 1, hf = r & 1;
      const float* Xbj = Xg + (size_t)(b0 + j) * (kT * kE);
      float cacc = 0.f;
#pragma unroll
      for (int i = 0; i < 64; ++i) {
        const int t2 = hf * 64 + i;
        if (t2 < kT) cacc += beta[j * 128 + t2] * Xbj[(size_t)t2 * kE + e];
      }
      cacc += __shfl_xor(cacc, 1, 64);
      if (hf == 0) ctxl[j * 128 + e] = cacc;
    }
    __syncthreads();
    if (tid < 256) {
      const int j = tid >> 6, l = tid & 63;
      float a2 = hl[j * 128 + l] * fcw[l] + hl[j * 128 + 64 + l] * fcw[64 + l]
               + ctxl[j * 128 + l] * fcw[128 + l] + ctxl[j * 128 + 64 + l] * fcw[192 + l];
      a2 = redsum64(a2);
      if (l == 0) out[b0 + j] = a2 + fcb[0];
    }
  }  // group loop
}
}  // namespace

extern "C" void kernel_launch(void* const* d_in, const int* in_sizes, int n_in,
                              void* d_out, int out_size, void* d_ws, size_t ws_size,
                              hipStream_t stream) {
  (void)in_sizes; (void)n_in; (void)d_ws; (void)ws_size; (void)out_size;
  const float* Xg    = (const float*)d_in[0];
  const float* yh    = (const float*)d_in[1];
  const float* vdw   = (const float*)d_in[2];
  const float* vdb   = (const float*)d_in[3];
  const float* Wdhs  = (const float*)d_in[4];
  const float* Wdhsb = (const float*)d_in[5];
  const float* Udw   = (const float*)d_in[6];
  const float* Udb   = (const float*)d_in[7];
  const float* ww    = (const float*)d_in[8];
  const float* wb    = (const float*)d_in[9];
  const float* Wih   = (const float*)d_in[10];
  const float* Whh   = (const float*)d_in[11];
  const float* bih   = (const float*)d_in[12];
  const float* bhh   = (const float*)d_in[13];
  const float* fcww  = (const float*)d_in[14];
  const float* fcb   = (const float*)d_in[15];
  float* out = (float*)d_out;

  hipFuncSetAttribute((const void*)decoder_kernel,
                      hipFuncAttributeMaxDynamicSharedMemorySize, kSmemBytes);
  decoder_kernel<<<dim3(kNWG), dim3(1024), kSmemBytes, stream>>>(
      Xg, yh, vdw, vdb, Wdhs, Wdhsb, Udw, Udb, ww, wb,
      Wih, Whh, bih, bhh, fcww, fcb, out);
}

// Round 14
// 4000.319 us; speedup vs baseline: 2.2038x; 1.1810x over previous
//
#include <hip/hip_runtime.h>
#include <hip/hip_bf16.h>

#if __has_builtin(__builtin_amdgcn_exp2f)
#define EXP2F(x) __builtin_amdgcn_exp2f(x)
#else
#define EXP2F(x) exp2f(x)
#endif
#if __has_builtin(__builtin_amdgcn_rcpf)
#define RCPF(x) __builtin_amdgcn_rcpf(x)
#else
#define RCPF(x) (1.0f/(x))
#endif

typedef _Float16 h2f16 __attribute__((ext_vector_type(2)));
typedef _Float16 f16x8 __attribute__((ext_vector_type(8)));
typedef float    f32x16 __attribute__((ext_vector_type(16)));

namespace {
constexpr int   kT   = 127;
constexpr int   kE   = 128;
constexpr int   kB   = 4096;
constexpr int   kNWG = 256;
constexpr int   kGRP = 4;                  // batches processed simultaneously
constexpr int   kBPW = 16;                 // batches per workgroup (4 groups)
constexpr float kLog2e = 1.4426950408889634f;
constexpr float kK2    = 2.8853900817779268f;   // 2*log2(e)
// u32: u2u 32768 + p2hA 256 + p2hB 256 + hc2 672 + wdb2h 64 + v2h 64 = 34080
// f32: act 2064 + sc/XW/yc/beta/hl/ctxl 6*512 + udbl 128 + fcw 256 + wwl 132 + biw 1024 = 6676
constexpr int   kSmemBytes = (34080 + 6676) * 4;   // 163024 <= 163840

__device__ __forceinline__ unsigned int packf16(float a, float b) {
  h2f16 h = { (_Float16)a, (_Float16)b };
  return __builtin_bit_cast(unsigned int, h);
}
__device__ __forceinline__ unsigned int pkaddf16(unsigned int a, unsigned int b) {
  h2f16 r = __builtin_bit_cast(h2f16, a) + __builtin_bit_cast(h2f16, b);
  return __builtin_bit_cast(unsigned int, r);
}

#if __has_builtin(__builtin_amdgcn_fdot2)
__device__ __forceinline__ float fdot2f(unsigned int a, unsigned int b, float c) {
  return __builtin_amdgcn_fdot2(__builtin_bit_cast(h2f16, a),
                                __builtin_bit_cast(h2f16, b), c, false);
}
#else
__device__ __forceinline__ float fdot2f(unsigned int a, unsigned int b, float c) {
  h2f16 ha = __builtin_bit_cast(h2f16, a), hb = __builtin_bit_cast(h2f16, b);
  return c + (float)ha.x * (float)hb.x + (float)ha.y * (float)hb.y;
}
#endif

// ---- DPP cross-lane (direction-symmetric controls only; r12/r13-validated) ----
template <int CTRL>
__device__ __forceinline__ float dppadd(float x) {
  return x + __int_as_float(__builtin_amdgcn_update_dpp(
      0, __float_as_int(x), CTRL, 0xF, 0xF, true));
}
template <int CTRL>
__device__ __forceinline__ float dppmov(float x) {
  return __int_as_float(__builtin_amdgcn_update_dpp(
      0, __float_as_int(x), CTRL, 0xF, 0xF, true));
}
__device__ __forceinline__ float redsum8dpp(float x) {   // sum over lane bits 0..2
  x = dppadd<0xB1>(x); x = dppadd<0x4E>(x); x = dppadd<0x141>(x);
  return x;
}
__device__ __forceinline__ float redsum64dpp(float x) {  // full-wave sum (4 DPP + 2 shfl)
  x = dppadd<0xB1>(x); x = dppadd<0x4E>(x); x = dppadd<0x141>(x); x = dppadd<0x128>(x);
  x += __shfl_xor(x, 16, 64);
  x += __shfl_xor(x, 32, 64);
  return x;
}
__device__ __forceinline__ float redsum64(float a) {
#pragma unroll
  for (int m = 1; m < 64; m <<= 1) a += __shfl_xor(a, m, 64);
  return a;
}

// 1024 threads, 16 waves, 4 batches per step-group, 3 barriers/step.
// Gates: MFMA, 16 row-tiles of row-interleaved Whh (row' = 4d+gate), K=128.
// Proj:  MFMA on waves 0-7: row-tile w&3 (of 4), K-half w>>2; halves packed
//        to p2hA/p2hB f16, summed in P3. K2 and bias folded in.
// P4: 512 threads, one LSTM cell (j,d) each; gates via one b128 act read.
__global__ __launch_bounds__(1024, 4) void decoder_kernel(
    const float* __restrict__ Xg,    // [B,127,128]
    const float* __restrict__ yh,    // [B,127]
    const float* __restrict__ vdw,   // [128]
    const float* __restrict__ vdb,   // [1]
    const float* __restrict__ Wdhs,  // [128,256]
    const float* __restrict__ Wdhsb, // [128]
    const float* __restrict__ Udw,   // [128,128]
    const float* __restrict__ Udb,   // [128]
    const float* __restrict__ ww,    // [129]
    const float* __restrict__ wb,    // [1]
    const float* __restrict__ Wih,   // [512]
    const float* __restrict__ Whh,   // [512,128]
    const float* __restrict__ bih,   // [512]
    const float* __restrict__ bhh,   // [512]
    const float* __restrict__ fcww,  // [256]
    const float* __restrict__ fcb,   // [1]
    float* __restrict__ out)         // [B]
{
  extern __shared__ char smem[];
  unsigned int* u2u   = (unsigned int*)smem;   // [4][128][64] f16 pairs; chunk c at c^(row&15)
  unsigned int* udw2  = u2u + 3 * 8192;        // staging scratch overlay on slot j=3
  unsigned int* p2hA  = u2u + 4 * 8192;        // [4][64] f16 pairs, proj K-half 0 (+bias, K2-scaled)
  unsigned int* p2hB  = p2hA + 256;            // [4][64] f16 pairs, proj K-half 1
  unsigned int* hc2   = p2hB + 256;            // [4][168]: 8 chunks of 16 u32 + 4 pad (stride 20)
  unsigned int* wdb2h = hc2 + 672;             // [64] f16 pairs of K2*W_dhs_b
  unsigned int* v2h   = wdb2h + 64;            // [64] f16 pairs of -2*v_d
  float* act  = (float*)(v2h + 64);   // [4][516] gate pre-activations, row' = 4d+gate
  float* sc   = act  + 2064;          // [4][128] raw scores
  float* XW   = sc   + 512;           // [4][128] ww . X[t,:]
  float* yc   = XW   + 512;           // [4][128] ww[128]*y + wb
  float* beta = yc   + 512;           // [4][128] softmax (last step only)
  float* hl   = beta + 512;           // [4][128] final h
  float* ctxl = hl   + 512;           // [4][128] final ctx
  float* udbl = ctxl + 512;           // [128]
  float* fcw  = udbl + 128;           // [256]
  float* wwl  = fcw  + 256;           // [132]
  float* biw  = wwl  + 132;           // [1024]: [4d+g]=bih+bhh, [512+4d+g]=Wih

  const int tid  = threadIdx.x;
  const int d8   = tid >> 3;          // 0..127
  const int sub  = tid & 7;
  const int lane = tid & 63;

  // ---- pinned per-thread weights: 64 persistent values (proven-safe zone) ----
  // whhA: gate MFMA A-frags (r13-verified template).
  unsigned int whhA[32];
  {
    const int wid = tid >> 6;
    const int rrA = lane & 31;
    const int rowA = (rrA & 3) * 128 + (8 * wid + (rrA >> 2));  // gate*128 + d
    const int kbA = (lane >> 5) * 8;
#pragma unroll
    for (int kk = 0; kk < 8; ++kk)
#pragma unroll
      for (int i2 = 0; i2 < 4; ++i2) {
        const int k = kk * 16 + kbA + 2 * i2;
        whhA[kk * 4 + i2] = packf16(Whh[rowA * 128 + k], Whh[rowA * 128 + k + 1]);
      }
  }
  // whhP: proj MFMA A-frags (K2-prescaled). Wave w&7: row-tile (w&3), K-half (w>>2)&1.
  unsigned int whhP[32];
  {
    const int wid8 = (tid >> 6) & 7;
    const int rt = wid8 & 3, kh = wid8 >> 2;
    const int rowP = rt * 32 + (lane & 31);
    const int kb = kh * 128 + (lane >> 5) * 8;
#pragma unroll
    for (int kk = 0; kk < 8; ++kk)
#pragma unroll
      for (int i2 = 0; i2 < 4; ++i2) {
        const int k = kb + kk * 16 + 2 * i2;
        whhP[kk * 4 + i2] = packf16(kK2 * Wdhs[rowP * 256 + k],
                                    kK2 * Wdhs[rowP * 256 + k + 1]);
      }
  }
#pragma unroll
  for (int p = 0; p < 32; ++p) asm volatile("" : "+v"(whhA[p]));
#pragma unroll
  for (int p = 0; p < 32; ++p) asm volatile("" : "+v"(whhP[p]));

  // ---- one-time constants ----
  if (tid < 132) wwl[tid] = (tid < 129) ? ww[tid] : ((tid == 129) ? wb[0] : 0.f);
  if (tid < 256) fcw[tid] = fcww[tid];
  if (tid < 128) udbl[tid] = Udb[tid];
  if (tid < 64) {
    wdb2h[tid] = packf16(kK2 * Wdhsb[2 * tid], kK2 * Wdhsb[2 * tid + 1]);
    v2h[tid]   = packf16(-2.0f * vdw[2 * tid], -2.0f * vdw[2 * tid + 1]);
  }
  if (tid < 512) {
    const int dd = tid >> 2, gg = tid & 3;
    biw[tid]       = bih[gg * 128 + dd] + bhh[gg * 128 + dd];
    biw[512 + tid] = Wih[gg * 128 + dd];
  }
  (void)vdb;   // constant shift, cancels in softmax

  for (int grp = 0; grp < kBPW / kGRP; ++grp) {
    const int b0 = blockIdx.x * kBPW + grp * kGRP;
    float creg = 0.f;                  // LSTM c for cell (tid>>7, tid&127), tids<512
    __syncthreads();   // previous group done with LDS

    // ---- S1: stage Udw f16 (swizzled) into slot3 scratch + init state/yc/XW pad ----
    {
      const int r = tid >> 3, mb = (tid & 7) * 2;
#pragma unroll
      for (int ch = 0; ch < 2; ++ch) {
        const int m = mb + ch;
        const float4 wa = *(const float4*)&Udw[r * kE + m * 8];
        const float4 wb4 = *(const float4*)&Udw[r * kE + m * 8 + 4];
        uint4 st;
        st.x = packf16(wa.x, wa.y);  st.y = packf16(wa.z, wa.w);
        st.z = packf16(wb4.x, wb4.y); st.w = packf16(wb4.z, wb4.w);
        *(uint4*)&udw2[r * 64 + ((m ^ (r >> 4)) << 2)] = st;
      }
    }
    if (tid < 672) hc2[tid] = 0u;
    if (tid < 512) {
      const int j = tid >> 7, s2 = tid & 127;
      yc[tid] = (s2 < kT) ? wwl[128] * yh[(size_t)(b0 + j) * kT + s2] + wwl[129] : 0.f;
      if (s2 == 127) XW[tid] = 0.f;
    }
    __syncthreads();

    // ---- S2: U2 = K2*(X @ Udw^T + Udb) (f16, swizzled) + XW, 4 batches ----
    uint4 st3a, st3b;
    if (d8 < kT) {
#pragma unroll
      for (int j = 0; j < kGRP; ++j) {
        const float* Xrow = Xg + (size_t)(b0 + j) * (kT * kE) + d8 * kE;
        float a = 0.f;
#pragma unroll
        for (int q = 0; q < 4; ++q) {
          const float4 xv = *(const float4*)&Xrow[sub * 16 + q * 4];
          const float4 wv = *(const float4*)&wwl[sub * 16 + q * 4];
          a += xv.x * wv.x + xv.y * wv.y + xv.z * wv.z + xv.w * wv.w;
        }
        a = redsum8dpp(a);
        if (sub == 0) XW[j * 128 + d8] = a;
        float acc[16];
#pragma unroll
        for (int jj = 0; jj < 16; ++jj) acc[jj] = 0.f;
        for (int m = 0; m < 16; ++m) {
          const float4 xa = *(const float4*)&Xrow[m * 8];
          const float4 xb4 = *(const float4*)&Xrow[m * 8 + 4];
          const unsigned int xp0 = packf16(xa.x, xa.y), xp1 = packf16(xa.z, xa.w);
          const unsigned int xp2 = packf16(xb4.x, xb4.y), xp3 = packf16(xb4.z, xb4.w);
#pragma unroll
          for (int jj = 0; jj < 16; ++jj) {
            const uint4 wq = *(const uint4*)&udw2[(sub * 16 + jj) * 64 + ((m ^ sub) << 2)];
            acc[jj] = fdot2f(xp3, wq.w, fdot2f(xp2, wq.z,
                      fdot2f(xp1, wq.y, fdot2f(xp0, wq.x, acc[jj]))));
          }
        }
        uint4 s0, s1;
        const int eb = sub * 16;
        s0.x = packf16(kK2 * (acc[0] + udbl[eb + 0]), kK2 * (acc[1] + udbl[eb + 1]));
        s0.y = packf16(kK2 * (acc[2] + udbl[eb + 2]), kK2 * (acc[3] + udbl[eb + 3]));
        s0.z = packf16(kK2 * (acc[4] + udbl[eb + 4]), kK2 * (acc[5] + udbl[eb + 5]));
        s0.w = packf16(kK2 * (acc[6] + udbl[eb + 6]), kK2 * (acc[7] + udbl[eb + 7]));
        s1.x = packf16(kK2 * (acc[8] + udbl[eb + 8]), kK2 * (acc[9] + udbl[eb + 9]));
        s1.y = packf16(kK2 * (acc[10] + udbl[eb + 10]), kK2 * (acc[11] + udbl[eb + 11]));
        s1.z = packf16(kK2 * (acc[12] + udbl[eb + 12]), kK2 * (acc[13] + udbl[eb + 13]));
        s1.w = packf16(kK2 * (acc[14] + udbl[eb + 14]), kK2 * (acc[15] + udbl[eb + 15]));
        if (j < 3) {
          *(uint4*)&u2u[j * 8192 + d8 * 64 + (((sub * 2 + 0) ^ (d8 & 15)) << 2)] = s0;
          *(uint4*)&u2u[j * 8192 + d8 * 64 + (((sub * 2 + 1) ^ (d8 & 15)) << 2)] = s1;
        } else { st3a = s0; st3b = s1; }
      }
    }
    __syncthreads();   // udw2 fully consumed
    if (d8 < kT) {
      *(uint4*)&u2u[3 * 8192 + d8 * 64 + (((sub * 2 + 0) ^ (d8 & 15)) << 2)] = st3a;
      *(uint4*)&u2u[3 * 8192 + d8 * 64 + (((sub * 2 + 1) ^ (d8 & 15)) << 2)] = st3b;
    }
    // (slot-3 stores separated from first read by B1 in the step loop)

    // ================= 127 steps x 4 batches, 3 barriers each =================
    for (int s = 0; s < kT; ++s) {
      // P1a: gate GEMV on MFMA (all 16 waves, r13-verified) -> act[]
      {
        f32x16 macc;
#pragma unroll
        for (int i = 0; i < 16; ++i) macc[i] = 0.f;
        const int jn = tid & 3;
        const int hi4 = ((tid >> 5) & 1) * 4;
#pragma unroll
        for (int kk = 0; kk < 8; ++kk) {
          const int p0 = kk * 8 + hi4;
          const uint4 bq = *(const uint4*)&hc2[jn * 168 + (p0 >> 4) * 20 + (p0 & 15)];
          const uint4 aq = {whhA[kk * 4 + 0], whhA[kk * 4 + 1],
                            whhA[kk * 4 + 2], whhA[kk * 4 + 3]};
          macc = __builtin_amdgcn_mfma_f32_32x32x16_f16(
              __builtin_bit_cast(f16x8, aq), __builtin_bit_cast(f16x8, bq),
              macc, 0, 0, 0);
        }
        if ((tid & 31) < 4) {
          const int wid = tid >> 6;
#pragma unroll
          for (int qq = 0; qq < 4; ++qq) {
            float4 v = {macc[qq * 4 + 0], macc[qq * 4 + 1],
                        macc[qq * 4 + 2], macc[qq * 4 + 3]};
            *(float4*)&act[(tid & 3) * 516 + 32 * wid + 8 * qq + hi4] = v;
          }
        }
      }
      // P1b: proj GEMV on MFMA (waves 0-7), halves to p2hA/p2hB f16
      if (tid < 512) {
        f32x16 pacc;
#pragma unroll
        for (int i = 0; i < 16; ++i) pacc[i] = 0.f;
        const int wid8 = tid >> 6;              // 0..7
        const int rt = wid8 & 3, kh = wid8 >> 2;
        const int jn = tid & 3;
        const int hi = (tid >> 5) & 1;
#pragma unroll
        for (int kk = 0; kk < 8; ++kk) {
          const int p0 = kh * 64 + kk * 8 + hi * 4;
          const uint4 bq = *(const uint4*)&hc2[jn * 168 + (p0 >> 4) * 20 + (p0 & 15)];
          const uint4 aq = {whhP[kk * 4 + 0], whhP[kk * 4 + 1],
                            whhP[kk * 4 + 2], whhP[kk * 4 + 3]};
          pacc = __builtin_amdgcn_mfma_f32_32x32x16_f16(
              __builtin_bit_cast(f16x8, aq), __builtin_bit_cast(f16x8, bq),
              pacc, 0, 0, 0);
        }
        if ((tid & 31) < 4) {
          const int j = tid & 31;
          unsigned int* dst = (kh == 0) ? p2hA : p2hB;
#pragma unroll
          for (int qq = 0; qq < 4; ++qq) {
            const int pr0 = rt * 16 + 4 * qq + 2 * hi;
            unsigned int pa0 = packf16(pacc[qq * 4 + 0], pacc[qq * 4 + 1]);
            unsigned int pa1 = packf16(pacc[qq * 4 + 2], pacc[qq * 4 + 3]);
            if (kh == 0) {
              pa0 = pkaddf16(pa0, wdb2h[pr0]);
              pa1 = pkaddf16(pa1, wdb2h[pr0 + 1]);
            }
            uint2 st = {pa0, pa1};
            *(uint2*)&dst[j * 64 + pr0] = st;
          }
        }
      }
      __syncthreads();  // B1

      // P3: score row d8, e-chunk [sub*16,+16): xs = u + pA + pB (f16 pk_add),
      //     f32 exp/rcp sigmoid (r8/r12-validated numerics).
      if (d8 < kT) {
        const int sw = d8 & 15;
        const uint4 vqa = *(const uint4*)&v2h[sub * 8];
        const uint4 vqb = *(const uint4*)&v2h[sub * 8 + 4];
        const unsigned int vv[8] = {vqa.x, vqa.y, vqa.z, vqa.w,
                                    vqb.x, vqb.y, vqb.z, vqb.w};
#pragma unroll
        for (int j = 0; j < kGRP; ++j) {
          const unsigned int* ur = u2u + j * 8192 + d8 * 64;
          const uint4 ua = *(const uint4*)&ur[(((sub * 2 + 0) ^ sw) << 2)];
          const uint4 ub = *(const uint4*)&ur[(((sub * 2 + 1) ^ sw) << 2)];
          const uint4 pa = *(const uint4*)&p2hA[j * 64 + sub * 8];
          const uint4 pb = *(const uint4*)&p2hA[j * 64 + sub * 8 + 4];
          const uint4 qa = *(const uint4*)&p2hB[j * 64 + sub * 8];
          const uint4 qb = *(const uint4*)&p2hB[j * 64 + sub * 8 + 4];
          const unsigned int uu[8] = {ua.x, ua.y, ua.z, ua.w, ub.x, ub.y, ub.z, ub.w};
          const unsigned int pp[8] = {pa.x, pa.y, pa.z, pa.w, pb.x, pb.y, pb.z, pb.w};
          const unsigned int qq2[8] = {qa.x, qa.y, qa.z, qa.w, qb.x, qb.y, qb.z, qb.w};
          float sacc = 0.f;
#pragma unroll
          for (int i = 0; i < 8; ++i) {
            const h2f16 xs = __builtin_bit_cast(h2f16, uu[i])
                           + __builtin_bit_cast(h2f16, pp[i])
                           + __builtin_bit_cast(h2f16, qq2[i]);
            const h2f16 vx = __builtin_bit_cast(h2f16, vv[i]);
            sacc += (float)vx.x * RCPF(1.f + EXP2F((float)xs.x));
            sacc += (float)vx.y * RCPF(1.f + EXP2F((float)xs.y));
          }
          sacc = redsum8dpp(sacc);
          if (sub == 0) sc[j * 128 + d8] = sacc;
        }
      }
      __syncthreads();  // B2

      // P4: 512 threads, one LSTM cell (j = tid>>7, dd = tid&127) each.
      if (tid < 512) {
        const int j = tid >> 7, dd = tid & 127, ln = tid & 63;
        const float e0v = EXP2F(sc[j * 128 + ln] * kLog2e);
        float e1v = 0.f, x1 = 0.f;
        if (ln < 63) {
          e1v = EXP2F(sc[j * 128 + 64 + ln] * kLog2e);
          x1 = XW[j * 128 + 64 + ln];
        }
        float num = e0v * XW[j * 128 + ln] + e1v * x1;
        float den = e0v + e1v;
        num = redsum64dpp(num);
        den = redsum64dpp(den);
        const float rden = RCPF(den);
        const float yt = num * rden + yc[j * 128 + s];
        const float4 a4 = *(const float4*)&act[j * 516 + 4 * dd];
        const float4 bi = *(const float4*)&biw[4 * dd];
        const float4 wi = *(const float4*)&biw[512 + 4 * dd];
        const float si = RCPF(1.f + EXP2F(-(a4.x + bi.x + yt * wi.x) * kLog2e));
        const float sf = RCPF(1.f + EXP2F(-(a4.y + bi.y + yt * wi.y) * kLog2e));
        const float tg = 1.f - 2.f * RCPF(1.f + EXP2F((a4.z + bi.z + yt * wi.z) * kK2));
        const float so = RCPF(1.f + EXP2F(-(a4.w + bi.w + yt * wi.w) * kLog2e));
        const float cn = sf * creg + si * tg;
        creg = cn;
        const float th = 1.f - 2.f * RCPF(1.f + EXP2F(cn * kK2));
        const float hn = so * th;
        const float ho = dppmov<0xB1>(hn);    // partner cell dd^1 (lane^1)
        const float co = dppmov<0xB1>(cn);
        if ((tid & 1) == 0) {
          const int p = dd >> 1;
          hc2[j * 168 + (p >> 4) * 20 + (p & 15)]       = packf16(hn, ho);
          hc2[j * 168 + (4 + (p >> 4)) * 20 + (p & 15)] = packf16(cn, co);
        }
        if (s == kT - 1) {
          hl[j * 128 + dd] = hn;
          beta[tid] = (dd < kT) ? EXP2F(sc[tid] * kLog2e) * rden : 0.f;
        }
      }
      __syncthreads();  // B3
    }  // steps

    // ---- final ctx in fp32 from global X; then fc (4 outputs) ----
    {
      const int j = tid >> 8, r = tid & 255, e = r >> 1, hf = r & 1;
      const float* Xbj = Xg + (size_t)(b0 + j) * (kT * kE);
      float cacc = 0.f;
#pragma unroll
      for (int i = 0; i < 64; ++i) {
        const int t2 = hf * 64 + i;
        if (t2 < kT) cacc += beta[j * 128 + t2] * Xbj[(size_t)t2 * kE + e];
      }
      cacc += __shfl_xor(cacc, 1, 64);
      if (hf == 0) ctxl[j * 128 + e] = cacc;
    }
    __syncthreads();
    if (tid < 256) {
      const int j = tid >> 6, l = tid & 63;
      float a2 = hl[j * 128 + l] * fcw[l] + hl[j * 128 + 64 + l] * fcw[64 + l]
               + ctxl[j * 128 + l] * fcw[128 + l] + ctxl[j * 128 + 64 + l] * fcw[192 + l];
      a2 = redsum64(a2);
      if (l == 0) out[b0 + j] = a2 + fcb[0];
    }
  }  // group loop
}
}  // namespace

extern "C" void kernel_launch(void* const* d_in, const int* in_sizes, int n_in,
                              void* d_out, int out_size, void* d_ws, size_t ws_size,
                              hipStream_t stream) {
  (void)in_sizes; (void)n_in; (void)d_ws; (void)ws_size; (void)out_size;
  const float* Xg    = (const float*)d_in[0];
  const float* yh    = (const float*)d_in[1];
  const float* vdw   = (const float*)d_in[2];
  const float* vdb   = (const float*)d_in[3];
  const float* Wdhs  = (const float*)d_in[4];
  const float* Wdhsb = (const float*)d_in[5];
  const float* Udw   = (const float*)d_in[6];
  const float* Udb   = (const float*)d_in[7];
  const float* ww    = (const float*)d_in[8];
  const float* wb    = (const float*)d_in[9];
  const float* Wih   = (const float*)d_in[10];
  const float* Whh   = (const float*)d_in[11];
  const float* bih   = (const float*)d_in[12];
  const float* bhh   = (const float*)d_in[13];
  const float* fcww  = (const float*)d_in[14];
  const float* fcb   = (const float*)d_in[15];
  float* out = (float*)d_out;

  hipFuncSetAttribute((const void*)decoder_kernel,
                      hipFuncAttributeMaxDynamicSharedMemorySize, kSmemBytes);
  decoder_kernel<<<dim3(kNWG), dim3(1024), kSmemBytes, stream>>>(
      Xg, yh, vdw, vdb, Wdhs, Wdhsb, Udw, Udb, ww, wb,
      Wih, Whh, bih, bhh, fcww, fcb, out);
}